// Round 7
// baseline (473.815 us; speedup 1.0000x reference)
//
#include <hip/hip_runtime.h>

#define N_NODES 100000
#define N_EDGES 1000000
#define SHIFT   4
#define NBUCK   6250          // 100000 >> 4
#define TPW     11            // tiles per wave (6144 waves x 11 >= 62500)

typedef __attribute__((ext_vector_type(8))) short bf16x8;
typedef __attribute__((ext_vector_type(4))) float f32x4;
typedef __attribute__((ext_vector_type(4))) unsigned u32x4;

static __device__ __forceinline__ short f2bf(float f) {
    unsigned u = __float_as_uint(f);
    u = (u + 0x7fffu + ((u >> 16) & 1u)) >> 16;
    return (short)u;
}
static __device__ __forceinline__ float bf2f(unsigned short s) {
    return __uint_as_float(((unsigned)s) << 16);
}
static __device__ __forceinline__ float lrelu(float x) {
    return fmaxf(x, 0.01f * x);
}
static __device__ __forceinline__ unsigned cvtpk(float lo, float hi) {
    unsigned r;
    asm("v_cvt_pk_bf16_f32 %0, %1, %2" : "=v"(r) : "v"(lo), "v"(hi));
    return r;
}
static __device__ __forceinline__ f32x4 ldnt_f4(const float* p) {
    return __builtin_nontemporal_load((const f32x4*)p);
}
static __device__ __forceinline__ unsigned long long ldnt_u64(const unsigned long long* p) {
    return __builtin_nontemporal_load(p);
}

// ---------------------------------------------------------------------------
// Sort pass 1: per-bucket histogram (bucket = origin >> 4).
// ---------------------------------------------------------------------------
__global__ __launch_bounds__(256) void sort_hist(
    const int* __restrict__ ei, unsigned* __restrict__ gh)
{
    __shared__ unsigned lh[NBUCK];
    const int t = threadIdx.x;
    for (int i = t; i < NBUCK; i += 256) lh[i] = 0;
    __syncthreads();
    for (int e = blockIdx.x * 256 + t; e < N_EDGES; e += gridDim.x * 256)
        atomicAdd(&lh[((unsigned)ei[e]) >> SHIFT], 1u);
    __syncthreads();
    for (int i = t; i < NBUCK; i += 256)
        if (lh[i]) atomicAdd(&gh[i], lh[i]);
}

// ---------------------------------------------------------------------------
// Sort pass 2: exclusive prefix sum of histogram -> cursor (1 block).
// ---------------------------------------------------------------------------
__global__ __launch_bounds__(256) void sort_scan(
    const unsigned* __restrict__ gh, unsigned* __restrict__ cursor)
{
    __shared__ unsigned lh[NBUCK];
    __shared__ unsigned sums[256];
    const int t = threadIdx.x;
    unsigned run = 0;
    #pragma unroll
    for (int j = 0; j < 25; ++j) {
        const int idx = t * 25 + j;
        if (idx < NBUCK) { lh[idx] = run; run += gh[idx]; }
    }
    sums[t] = run;
    __syncthreads();
    if (t == 0) {
        unsigned acc = 0;
        for (int i = 0; i < 256; ++i) { unsigned v = sums[i]; sums[i] = acc; acc += v; }
    }
    __syncthreads();
    const unsigned base = sums[t];
    #pragma unroll
    for (int j = 0; j < 25; ++j) {
        const int idx = t * 25 + j;
        if (idx < NBUCK) cursor[idx] = lh[idx] + base;
    }
}

// ---------------------------------------------------------------------------
// Sort pass 3: scatter edges into bucket order, packed u64:
//   bits [0,20) = oi, [20,40) = di, [40,60) = original edge id.
// ---------------------------------------------------------------------------
__global__ __launch_bounds__(256) void sort_scatter(
    const int* __restrict__ ei, unsigned* __restrict__ cursor,
    unsigned long long* __restrict__ so)
{
    for (int e = blockIdx.x * 256 + threadIdx.x; e < N_EDGES; e += gridDim.x * 256) {
        const unsigned oi = (unsigned)ei[e];
        const unsigned di = (unsigned)ei[N_EDGES + e];
        const unsigned pos = atomicAdd(&cursor[oi >> SHIFT], 1u);
        so[pos] = (unsigned long long)oi
                | ((unsigned long long)di << 20)
                | ((unsigned long long)e  << 40);
    }
}

// ---------------------------------------------------------------------------
// Precompute: P/Q as bf16 in gather-swizzled layout (unchanged).
// ---------------------------------------------------------------------------
__global__ __launch_bounds__(256) void precompute_mfma(
    const float* __restrict__ x, const float* __restrict__ W1,
    const float* __restrict__ b1, unsigned short* __restrict__ Pb,
    unsigned short* __restrict__ Qb)
{
    const int t    = threadIdx.x;
    const int lane = t & 63;
    const int w    = t >> 6;
    const int q    = lane >> 4;
    const int n15  = lane & 15;
    const int chb  = 64 * w;

    bf16x8 afrag[4][4];
    #pragma unroll
    for (int mtl = 0; mtl < 4; ++mtl) {
        const int ch = chb + 16 * mtl + n15;
        const float* wcol = (ch < 128) ? (W1 + ch) : (W1 + 128 * 128 + (ch - 128));
        #pragma unroll
        for (int ks = 0; ks < 4; ++ks)
            #pragma unroll
            for (int j = 0; j < 8; ++j)
                afrag[mtl][ks][j] = f2bf(wcol[(size_t)(32 * ks + 8 * q + j) * 128]);
    }
    float b1r[16];
    #pragma unroll
    for (int mtl = 0; mtl < 4; ++mtl)
        #pragma unroll
        for (int r = 0; r < 4; ++r) {
            const int ch = chb + 16 * mtl + 4 * q + r;
            b1r[mtl * 4 + r] = (ch < 128) ? b1[ch] : 0.0f;
        }

    unsigned short* tbase = (w < 2) ? Pb : Qb;
    const int mtb = 4 * (w & 1);

    for (int tile = blockIdx.x; tile < N_NODES / 16; tile += gridDim.x) {
        const int n0 = tile * 16;
        const float* xrow = x + (size_t)(n0 + n15) * 128;

        bf16x8 bfr[4];
        #pragma unroll
        for (int ks = 0; ks < 4; ++ks) {
            f32x4 xa = ldnt_f4(xrow + 32 * ks + 8 * q);
            f32x4 xb = ldnt_f4(xrow + 32 * ks + 8 * q + 4);
            u32x4 bu;
            bu[0] = cvtpk(xa[0], xa[1]);
            bu[1] = cvtpk(xa[2], xa[3]);
            bu[2] = cvtpk(xb[0], xb[1]);
            bu[3] = cvtpk(xb[2], xb[3]);
            bfr[ks] = __builtin_bit_cast(bf16x8, bu);
        }
        #pragma unroll
        for (int mtl = 0; mtl < 4; ++mtl) {
            f32x4 acc = {0.f, 0.f, 0.f, 0.f};
            #pragma unroll
            for (int ks = 0; ks < 4; ++ks)
                acc = __builtin_amdgcn_mfma_f32_16x16x32_bf16(afrag[mtl][ks], bfr[ks], acc, 0, 0, 0);
            unsigned* dst = (unsigned*)(tbase + (size_t)(n0 + n15) * 128 + q * 32 + (mtb + mtl) * 4);
            dst[0] = cvtpk(acc[0] + b1r[mtl * 4 + 0], acc[1] + b1r[mtl * 4 + 1]);
            dst[1] = cvtpk(acc[2] + b1r[mtl * 4 + 2], acc[3] + b1r[mtl * 4 + 3]);
        }
    }
}

// ---------------------------------------------------------------------------
// Edge kernel v7: processes ORIGIN-SORTED edges in contiguous per-wave
// chunks. A wave's P-gathers stay inside a ~4-KB node window (bucket of 16
// nodes) -> L1/L2-hit instead of random L2-miss; the random-miss demand on
// the memory system (the R3/R6-proven shared bottleneck) drops by ~half.
// Q-gathers remain random (irreducible single-key sort). ef is now a random
// single-use 128-B gather (same line count as streaming). out is a
// scattered 4-B nt store. Structure otherwise = clean v5 (64 VGPR, no dbuf).
// ---------------------------------------------------------------------------
__global__ __launch_bounds__(256, 3) void edge_mfma(
    const unsigned long long* __restrict__ so, const float* __restrict__ ef,
    const float* __restrict__ W1, const float* __restrict__ W2,
    const float* __restrict__ b2, const float* __restrict__ W3,
    const float* __restrict__ b3, const unsigned short* __restrict__ Pb,
    const unsigned short* __restrict__ Qb, float* __restrict__ out)
{
    __shared__ unsigned short w2s[16 * 64 * 8];
    __shared__ unsigned short a1s[8 * 64 * 8];
    const int t    = threadIdx.x;
    const int lane = t & 63;
    const int w    = t >> 6;
    const int q    = lane >> 4;
    const int n15  = lane & 15;

    #pragma unroll
    for (int i = 0; i < 2; ++i) {
        const int mt = 2 * w + i;
        bf16x8 f;
        #pragma unroll
        for (int j = 0; j < 8; ++j)
            f[j] = f2bf(W1[(size_t)(256 + 8 * q + j) * 128 + 16 * mt + n15]);
        *(bf16x8*)&a1s[(mt * 64 + lane) * 8] = f;
    }
    {
        const int mt2 = w;
        #pragma unroll
        for (int ks = 0; ks < 4; ++ks) {
            bf16x8 f;
            #pragma unroll
            for (int j = 0; j < 8; ++j) {
                const int ch = 32 * ks + ((j < 4) ? (4 * q + j) : (16 + 4 * q + (j - 4)));
                f[j] = f2bf(W2[(size_t)ch * 64 + 16 * mt2 + n15]);
            }
            *(bf16x8*)&w2s[(((mt2 << 2) | ks) * 64 + lane) * 8] = f;
        }
    }
    unsigned b2w3[16];
    #pragma unroll
    for (int mt2 = 0; mt2 < 4; ++mt2)
        #pragma unroll
        for (int r = 0; r < 4; ++r) {
            const int ch = 16 * mt2 + 4 * q + r;
            b2w3[mt2 * 4 + r] = (unsigned)(unsigned short)f2bf(b2[ch])
                              | ((unsigned)(unsigned short)f2bf(W3[ch]) << 16);
        }
    const float b3v = b3[0];

    __syncthreads();

    const int nTiles = N_EDGES / 16;           // 62500
    const int wv     = blockIdx.x * 4 + w;
    const int base   = wv * TPW;
    if (base >= nTiles) return;
    const int tileEnd = min(base + TPW, nTiles);

    int tile0 = base, tile1 = base + 1;
    bool have1 = tile1 < tileEnd;

    // gen-0
    int oi0, di0, eid0; f32x4 ea0, eb0;
    {
        const unsigned long long s0 = ldnt_u64(&so[(size_t)tile0 * 16 + n15]);
        oi0 = (int)(s0 & 0xFFFFFu); di0 = (int)((s0 >> 20) & 0xFFFFFu); eid0 = (int)(s0 >> 40);
        ea0 = ldnt_f4(ef + (size_t)eid0 * 32 + 8 * q);
        eb0 = ldnt_f4(ef + (size_t)eid0 * 32 + 8 * q + 4);
    }
    // gen-1
    int oi1 = oi0, di1 = di0, eid1 = eid0; f32x4 ea1 = ea0, eb1 = eb0;
    if (have1) {
        const unsigned long long s1 = ldnt_u64(&so[(size_t)tile1 * 16 + n15]);
        oi1 = (int)(s1 & 0xFFFFFu); di1 = (int)((s1 >> 20) & 0xFFFFFu); eid1 = (int)(s1 >> 40);
        ea1 = ldnt_f4(ef + (size_t)eid1 * 32 + 8 * q);
        eb1 = ldnt_f4(ef + (size_t)eid1 * 32 + 8 * q + 4);
    }
    bf16x8 pvb[4], qvb[4];
    {
        const unsigned short* prow = Pb + (size_t)oi0 * 128 + q * 32;
        const unsigned short* qrow = Qb + (size_t)di0 * 128 + q * 32;
        #pragma unroll
        for (int c = 0; c < 4; ++c) {
            pvb[c] = *(const bf16x8*)(prow + 8 * c);
            qvb[c] = *(const bf16x8*)(qrow + 8 * c);
        }
    }

    while (true) {
        u32x4 befu;
        befu[0] = cvtpk(ea0[0], ea0[1]);
        befu[1] = cvtpk(ea0[2], ea0[3]);
        befu[2] = cvtpk(eb0[0], eb0[1]);
        befu[3] = cvtpk(eb0[2], eb0[3]);
        const bf16x8 bef = __builtin_bit_cast(bf16x8, befu);

        // gen-2 prefetch (sorted-list entry + its edge features)
        const int  tile2 = tile1 + 1;
        const bool have2 = have1 && (tile2 < tileEnd);
        int oi2 = oi1, di2 = di1, eid2 = eid1; f32x4 ea2 = ea1, eb2 = eb1;
        if (have2) {
            const unsigned long long s2 = ldnt_u64(&so[(size_t)tile2 * 16 + n15]);
            oi2 = (int)(s2 & 0xFFFFFu); di2 = (int)((s2 >> 20) & 0xFFFFFu); eid2 = (int)(s2 >> 40);
            ea2 = ldnt_f4(ef + (size_t)eid2 * 32 + 8 * q);
            eb2 = ldnt_f4(ef + (size_t)eid2 * 32 + 8 * q + 4);
        }

        // phase 1: 8 MFMA + epilogue -> hfu
        u32x4 hfu[4];
        #pragma unroll
        for (int mt = 0; mt < 8; ++mt) {
            const bf16x8 a1f = *(const bf16x8*)&a1s[(mt * 64 + lane) * 8];
            f32x4 z = {0.f, 0.f, 0.f, 0.f};
            f32x4 h = __builtin_amdgcn_mfma_f32_16x16x32_bf16(a1f, bef, z, 0, 0, 0);
            const int c = mt >> 1, off = (mt & 1) * 4;
            float v0 = lrelu(h[0] + bf2f((unsigned short)pvb[c][off + 0]) + bf2f((unsigned short)qvb[c][off + 0]));
            float v1 = lrelu(h[1] + bf2f((unsigned short)pvb[c][off + 1]) + bf2f((unsigned short)qvb[c][off + 1]));
            float v2 = lrelu(h[2] + bf2f((unsigned short)pvb[c][off + 2]) + bf2f((unsigned short)qvb[c][off + 2]));
            float v3 = lrelu(h[3] + bf2f((unsigned short)pvb[c][off + 3]) + bf2f((unsigned short)qvb[c][off + 3]));
            hfu[mt >> 1][(mt & 1) * 2 + 0] = cvtpk(v0, v1);
            hfu[mt >> 1][(mt & 1) * 2 + 1] = cvtpk(v2, v3);
        }

        // gathers for next tile (P local via sort; Q random)
        if (have1) {
            const unsigned short* prow = Pb + (size_t)oi1 * 128 + q * 32;
            const unsigned short* qrow = Qb + (size_t)di1 * 128 + q * 32;
            #pragma unroll
            for (int c = 0; c < 4; ++c) {
                pvb[c] = *(const bf16x8*)(prow + 8 * c);
                qvb[c] = *(const bf16x8*)(qrow + 8 * c);
            }
        }

        // phase 2: 16 MFMA
        f32x4 acc2[4] = {{0.f,0.f,0.f,0.f},{0.f,0.f,0.f,0.f},{0.f,0.f,0.f,0.f},{0.f,0.f,0.f,0.f}};
        #pragma unroll
        for (int ks = 0; ks < 4; ++ks) {
            const bf16x8 hfrag = __builtin_bit_cast(bf16x8, hfu[ks]);
            #pragma unroll
            for (int mt2 = 0; mt2 < 4; ++mt2) {
                const bf16x8 a2f = *(const bf16x8*)&w2s[(((mt2 << 2) | ks) * 64 + lane) * 8];
                acc2[mt2] = __builtin_amdgcn_mfma_f32_16x16x32_bf16(a2f, hfrag, acc2[mt2], 0, 0, 0);
            }
        }

        // phase 3: bias, leaky, dot W3, reduce, scattered store to out[eid]
        float s = 0.0f;
        #pragma unroll
        for (int mt2 = 0; mt2 < 4; ++mt2)
            #pragma unroll
            for (int r = 0; r < 4; ++r) {
                const unsigned u = b2w3[mt2 * 4 + r];
                float v = acc2[mt2][r] + bf2f((unsigned short)(u & 0xffffu));
                v = lrelu(v);
                s += v * __uint_as_float(u & 0xffff0000u);
            }
        s += __shfl_xor(s, 16);
        s += __shfl_xor(s, 32);
        if (q == 0) __builtin_nontemporal_store(s + b3v, &out[eid0]);

        if (!have1) break;
        tile0 = tile1; tile1 = tile2; have1 = have2;
        oi1 = oi2; di1 = di2;
        eid0 = eid1; eid1 = eid2;
        ea0 = ea1; eb0 = eb1; ea1 = ea2; eb1 = eb2;
    }
}

extern "C" void kernel_launch(void* const* d_in, const int* in_sizes, int n_in,
                              void* d_out, int out_size, void* d_ws, size_t ws_size,
                              hipStream_t stream) {
    const float* x   = (const float*)d_in[0];
    const int*   ei  = (const int*)d_in[1];
    const float* ef  = (const float*)d_in[2];
    const float* W1  = (const float*)d_in[3];
    const float* b1  = (const float*)d_in[4];
    const float* W2  = (const float*)d_in[5];
    const float* b2  = (const float*)d_in[6];
    const float* W3  = (const float*)d_in[7];
    const float* b3  = (const float*)d_in[8];
    float*       out = (float*)d_out;

    // ws layout (59.3 MB):
    //   Pb  [100000][128] bf16  : 25.6 MB
    //   Qb  [100000][128] bf16  : 25.6 MB
    //   so  [1M] u64 sorted edges: 8 MB
    //   gh / cursor             : 2 x 25 KB
    unsigned short* Pb = (unsigned short*)d_ws;
    unsigned short* Qb = Pb + (size_t)N_NODES * 128;
    unsigned long long* so = (unsigned long long*)(Qb + (size_t)N_NODES * 128);
    unsigned* gh     = (unsigned*)(so + (size_t)N_EDGES);
    unsigned* cursor = gh + NBUCK;

    hipMemsetAsync(gh, 0, NBUCK * sizeof(unsigned), stream);
    sort_hist   <<<256, 256, 0, stream>>>(ei, gh);
    sort_scan   <<<1,   256, 0, stream>>>(gh, cursor);
    sort_scatter<<<1024,256, 0, stream>>>(ei, cursor, so);
    precompute_mfma<<<512, 256, 0, stream>>>(x, W1, b1, Pb, Qb);
    edge_mfma<<<1536, 256, 0, stream>>>(so, ef, W1, W2, b2, W3, b3, Pb, Qb, out);
}

// Round 9
// 354.236 us; speedup vs baseline: 1.3376x; 1.3376x over previous
//
#include <hip/hip_runtime.h>

#define N_NODES 100000
#define N_EDGES 1000000

typedef __attribute__((ext_vector_type(8))) short bf16x8;
typedef __attribute__((ext_vector_type(4))) float f32x4;
typedef __attribute__((ext_vector_type(4))) unsigned u32x4;

static __device__ __forceinline__ short f2bf(float f) {
    unsigned u = __float_as_uint(f);
    u = (u + 0x7fffu + ((u >> 16) & 1u)) >> 16;
    return (short)u;
}
static __device__ __forceinline__ float bf2f(unsigned short s) {
    return __uint_as_float(((unsigned)s) << 16);
}
static __device__ __forceinline__ float lrelu(float x) {
    return fmaxf(x, 0.01f * x);   // 0.01x > x iff x < 0
}
// packed f32->bf16 (RNE)
static __device__ __forceinline__ unsigned cvtpk(float lo, float hi) {
    unsigned r;
    asm("v_cvt_pk_bf16_f32 %0, %1, %2" : "=v"(r) : "v"(lo), "v"(hi));
    return r;
}
// non-temporal helpers: single-use streams must not pollute caches
static __device__ __forceinline__ f32x4 ldnt_f4(const float* p) {
    return __builtin_nontemporal_load((const f32x4*)p);
}
static __device__ __forceinline__ int ldnt_i(const int* p) {
    return __builtin_nontemporal_load(p);
}

// ---------------------------------------------------------------------------
// Precompute v2: P/Q as bf16 in gather-swizzled layout.
// W1-fragment setup restructured: the old per-thread build did 128 strided
// (512-B) scalar global loads -> 64-way transaction split per instruction,
// ~16M redundant L1 transactions across the grid. Now each block stages W1
// rows 0..255 with COALESCED loads into LDS, transposed to w1t[col][row]
// (bf16, row-stride 264 -> 16-B aligned), and fragment build is 16
// ds_read_b128 per thread. Table stores are non-temporal (51 MB >> L2).
// ---------------------------------------------------------------------------
__global__ __launch_bounds__(256) void precompute_mfma(
    const float* __restrict__ x, const float* __restrict__ W1,
    const float* __restrict__ b1, unsigned short* __restrict__ Pb,
    unsigned short* __restrict__ Qb)
{
    __shared__ unsigned short w1t[128][264];   // [col][row], 67.6 KB -> 2 blocks/CU
    const int t    = threadIdx.x;
    const int lane = t & 63;
    const int w    = t >> 6;
    const int q    = lane >> 4;
    const int n15  = lane & 15;
    const int chb  = 64 * w;

    // stage W1 rows 0..255 (the x_o / x_d blocks), coalesced read, transposed
    #pragma unroll 4
    for (int i = 0; i < 128; ++i) {
        const int idx = t + 256 * i;           // 0..32767
        const int row = idx >> 7, col = idx & 127;
        w1t[col][row] = (unsigned short)f2bf(W1[idx]);
    }
    __syncthreads();

    // fragment build from LDS (b128, 16-B aligned: 528*tc + 2*rb + 64*ks + 16*q)
    bf16x8 afrag[4][4];
    #pragma unroll
    for (int mtl = 0; mtl < 4; ++mtl) {
        const int ch = chb + 16 * mtl + n15;
        const int tc = (ch < 128) ? ch : (ch - 128);
        const int rb = (ch < 128) ? 0 : 128;
        #pragma unroll
        for (int ks = 0; ks < 4; ++ks)
            afrag[mtl][ks] = *(const bf16x8*)&w1t[tc][rb + 32 * ks + 8 * q];
    }
    float b1r[16];
    #pragma unroll
    for (int mtl = 0; mtl < 4; ++mtl)
        #pragma unroll
        for (int r = 0; r < 4; ++r) {
            const int ch = chb + 16 * mtl + 4 * q + r;
            b1r[mtl * 4 + r] = (ch < 128) ? b1[ch] : 0.0f;
        }

    unsigned short* tbase = (w < 2) ? Pb : Qb;
    const int mtb = 4 * (w & 1);   // mt base within table

    for (int tile = blockIdx.x; tile < N_NODES / 16; tile += gridDim.x) {
        const int n0 = tile * 16;
        const float* xrow = x + (size_t)(n0 + n15) * 128;

        bf16x8 bfr[4];
        #pragma unroll
        for (int ks = 0; ks < 4; ++ks) {
            f32x4 xa = ldnt_f4(xrow + 32 * ks + 8 * q);
            f32x4 xb = ldnt_f4(xrow + 32 * ks + 8 * q + 4);
            u32x4 bu;
            bu[0] = cvtpk(xa[0], xa[1]);
            bu[1] = cvtpk(xa[2], xa[3]);
            bu[2] = cvtpk(xb[0], xb[1]);
            bu[3] = cvtpk(xb[2], xb[3]);
            bfr[ks] = __builtin_bit_cast(bf16x8, bu);
        }
        #pragma unroll
        for (int mtl = 0; mtl < 4; ++mtl) {
            f32x4 acc = {0.f, 0.f, 0.f, 0.f};
            #pragma unroll
            for (int ks = 0; ks < 4; ++ks)
                acc = __builtin_amdgcn_mfma_f32_16x16x32_bf16(afrag[mtl][ks], bfr[ks], acc, 0, 0, 0);
            unsigned* dst = (unsigned*)(tbase + (size_t)(n0 + n15) * 128 + q * 32 + (mtb + mtl) * 4);
            __builtin_nontemporal_store(cvtpk(acc[0] + b1r[mtl * 4 + 0], acc[1] + b1r[mtl * 4 + 1]), dst);
            __builtin_nontemporal_store(cvtpk(acc[2] + b1r[mtl * 4 + 2], acc[3] + b1r[mtl * 4 + 3]), dst + 1);
        }
    }
}

// ---------------------------------------------------------------------------
// Edge kernel v5 (exact revert — best measured: 110 µs, spill-free, 64 VGPR):
// no LDS round-trip (k-permuted W2 frags), single-buffered gathers issued
// after phase 1, 2-deep idx/ef prefetch, nt on single-use streams.
// ---------------------------------------------------------------------------
__global__ __launch_bounds__(256, 3) void edge_mfma(
    const int* __restrict__ ei, const float* __restrict__ ef,
    const float* __restrict__ W1, const float* __restrict__ W2,
    const float* __restrict__ b2, const float* __restrict__ W3,
    const float* __restrict__ b3, const unsigned short* __restrict__ Pb,
    const unsigned short* __restrict__ Qb, float* __restrict__ out)
{
    __shared__ unsigned short w2s[16 * 64 * 8];   // 16 frags x 64 lanes x 16B = 16 KiB
    __shared__ unsigned short a1s[8 * 64 * 8];    // 8 frags x 64 lanes x 16B  =  8 KiB
    const int t    = threadIdx.x;
    const int lane = t & 63;
    const int w    = t >> 6;
    const int q    = lane >> 4;
    const int n15  = lane & 15;

    // stage W1c^T frags (edge-feature slice): wave w writes mt = 2w, 2w+1
    #pragma unroll
    for (int i = 0; i < 2; ++i) {
        const int mt = 2 * w + i;
        bf16x8 f;
        #pragma unroll
        for (int j = 0; j < 8; ++j)
            f[j] = f2bf(W1[(size_t)(256 + 8 * q + j) * 128 + 16 * mt + n15]);
        *(bf16x8*)&a1s[(mt * 64 + lane) * 8] = f;
    }

    // stage W2^T frags in PERMUTED k-order: wave w writes mt2 = w
    // chunk ks, lane q, reg j  <->  channel 32ks + (j<4 ? 4q+j : 16+4q+j-4)
    {
        const int mt2 = w;
        #pragma unroll
        for (int ks = 0; ks < 4; ++ks) {
            bf16x8 f;
            #pragma unroll
            for (int j = 0; j < 8; ++j) {
                const int ch = 32 * ks + ((j < 4) ? (4 * q + j) : (16 + 4 * q + (j - 4)));
                f[j] = f2bf(W2[(size_t)ch * 64 + 16 * mt2 + n15]);
            }
            *(bf16x8*)&w2s[(((mt2 << 2) | ks) * 64 + lane) * 8] = f;
        }
    }

    // b2 / W3 packed as bf16 pairs (low = b2, high = W3)
    unsigned b2w3[16];
    #pragma unroll
    for (int mt2 = 0; mt2 < 4; ++mt2)
        #pragma unroll
        for (int r = 0; r < 4; ++r) {
            const int ch = 16 * mt2 + 4 * q + r;
            b2w3[mt2 * 4 + r] = (unsigned)(unsigned short)f2bf(b2[ch])
                              | ((unsigned)(unsigned short)f2bf(W3[ch]) << 16);
        }
    const float b3v = b3[0];

    __syncthreads();   // a1s/w2s visible to all waves (only barrier in the kernel)

    const int nTiles  = N_EDGES / 16;          // 62500
    const int wid     = blockIdx.x * 4 + w;
    const int wstride = gridDim.x * 4;
    if (wid >= nTiles) return;

    // ---- prologue: generations 0 (idx+ef+gather) and 1 (idx+ef) ----
    int tile0 = wid;
    int tile1 = tile0 + wstride;
    bool have1 = tile1 < nTiles;

    int oi0, di0; f32x4 ea0, eb0;
    {
        const int e0 = tile0 * 16;
        oi0 = ldnt_i(&ei[e0 + n15]);
        di0 = ldnt_i(&ei[N_EDGES + e0 + n15]);
        ea0 = ldnt_f4(ef + (size_t)(e0 + n15) * 32 + 8 * q);
        eb0 = ldnt_f4(ef + (size_t)(e0 + n15) * 32 + 8 * q + 4);
    }
    int oi1 = 0, di1 = 0; f32x4 ea1 = ea0, eb1 = eb0;
    if (have1) {
        const int e1 = tile1 * 16;
        oi1 = ldnt_i(&ei[e1 + n15]);
        di1 = ldnt_i(&ei[N_EDGES + e1 + n15]);
        ea1 = ldnt_f4(ef + (size_t)(e1 + n15) * 32 + 8 * q);
        eb1 = ldnt_f4(ef + (size_t)(e1 + n15) * 32 + 8 * q + 4);
    }
    bf16x8 pvb[4], qvb[4];
    {
        const unsigned short* prow = Pb + (size_t)oi0 * 128 + q * 32;
        const unsigned short* qrow = Qb + (size_t)di0 * 128 + q * 32;
        #pragma unroll
        for (int c = 0; c < 4; ++c) {
            pvb[c] = *(const bf16x8*)(prow + 8 * c);
            qvb[c] = *(const bf16x8*)(qrow + 8 * c);
        }
    }

    while (true) {
        // convert current ef to B-frag
        u32x4 befu;
        befu[0] = cvtpk(ea0[0], ea0[1]);
        befu[1] = cvtpk(ea0[2], ea0[3]);
        befu[2] = cvtpk(eb0[0], eb0[1]);
        befu[3] = cvtpk(eb0[2], eb0[3]);
        const bf16x8 bef = __builtin_bit_cast(bf16x8, befu);

        // issue generation-2 idx + ef loads (consumed next-next iteration)
        const int  tile2 = tile1 + wstride;
        const bool have2 = have1 && (tile2 < nTiles);
        int oi2 = oi1, di2 = di1; f32x4 ea2 = ea1, eb2 = eb1;
        if (have2) {
            const int e2 = tile2 * 16;
            oi2 = ldnt_i(&ei[e2 + n15]);
            di2 = ldnt_i(&ei[N_EDGES + e2 + n15]);
            ea2 = ldnt_f4(ef + (size_t)(e2 + n15) * 32 + 8 * q);
            eb2 = ldnt_f4(ef + (size_t)(e2 + n15) * 32 + 8 * q + 4);
        }

        // ---- phase 1: 8 MFMA + epilogue -> hfu (registers, no LDS) ----
        u32x4 hfu[4];
        #pragma unroll
        for (int mt = 0; mt < 8; ++mt) {
            const bf16x8 a1f = *(const bf16x8*)&a1s[(mt * 64 + lane) * 8];
            f32x4 z = {0.f, 0.f, 0.f, 0.f};
            f32x4 h = __builtin_amdgcn_mfma_f32_16x16x32_bf16(a1f, bef, z, 0, 0, 0);
            const int c = mt >> 1, off = (mt & 1) * 4;
            float v0 = lrelu(h[0] + bf2f((unsigned short)pvb[c][off + 0]) + bf2f((unsigned short)qvb[c][off + 0]));
            float v1 = lrelu(h[1] + bf2f((unsigned short)pvb[c][off + 1]) + bf2f((unsigned short)qvb[c][off + 1]));
            float v2 = lrelu(h[2] + bf2f((unsigned short)pvb[c][off + 2]) + bf2f((unsigned short)qvb[c][off + 2]));
            float v3 = lrelu(h[3] + bf2f((unsigned short)pvb[c][off + 3]) + bf2f((unsigned short)qvb[c][off + 3]));
            hfu[mt >> 1][(mt & 1) * 2 + 0] = cvtpk(v0, v1);
            hfu[mt >> 1][(mt & 1) * 2 + 1] = cvtpk(v2, v3);
        }

        // pvb/qvb now dead: issue next tile's gathers (indices loaded a full
        // iteration ago -> no address-dependency stall here). Cached (L3).
        if (have1) {
            const unsigned short* prow = Pb + (size_t)oi1 * 128 + q * 32;
            const unsigned short* qrow = Qb + (size_t)di1 * 128 + q * 32;
            #pragma unroll
            for (int c = 0; c < 4; ++c) {
                pvb[c] = *(const bf16x8*)(prow + 8 * c);
                qvb[c] = *(const bf16x8*)(qrow + 8 * c);
            }
        }

        // ---- phase 2: 16 MFMA, B-operand straight from hfu registers ----
        f32x4 acc2[4] = {{0.f,0.f,0.f,0.f},{0.f,0.f,0.f,0.f},{0.f,0.f,0.f,0.f},{0.f,0.f,0.f,0.f}};
        #pragma unroll
        for (int ks = 0; ks < 4; ++ks) {
            const bf16x8 hfrag = __builtin_bit_cast(bf16x8, hfu[ks]);
            #pragma unroll
            for (int mt2 = 0; mt2 < 4; ++mt2) {
                const bf16x8 a2f = *(const bf16x8*)&w2s[(((mt2 << 2) | ks) * 64 + lane) * 8];
                acc2[mt2] = __builtin_amdgcn_mfma_f32_16x16x32_bf16(a2f, hfrag, acc2[mt2], 0, 0, 0);
            }
        }

        // ---- phase 3: bias, leaky, dot W3, 4-way lane reduce ----
        float s = 0.0f;
        #pragma unroll
        for (int mt2 = 0; mt2 < 4; ++mt2)
            #pragma unroll
            for (int r = 0; r < 4; ++r) {
                const unsigned u = b2w3[mt2 * 4 + r];
                float v = acc2[mt2][r] + bf2f((unsigned short)(u & 0xffffu));
                v = lrelu(v);
                s += v * __uint_as_float(u & 0xffff0000u);
            }
        s += __shfl_xor(s, 16);
        s += __shfl_xor(s, 32);
        if (q == 0) __builtin_nontemporal_store(s + b3v, &out[tile0 * 16 + n15]);

        if (!have1) break;
        tile0 = tile1; tile1 = tile2; have1 = have2;
        oi1 = oi2; di1 = di2;
        ea0 = ea1; eb0 = eb1; ea1 = ea2; eb1 = eb2;
    }
}

extern "C" void kernel_launch(void* const* d_in, const int* in_sizes, int n_in,
                              void* d_out, int out_size, void* d_ws, size_t ws_size,
                              hipStream_t stream) {
    const float* x   = (const float*)d_in[0];
    const int*   ei  = (const int*)d_in[1];
    const float* ef  = (const float*)d_in[2];
    const float* W1  = (const float*)d_in[3];
    const float* b1  = (const float*)d_in[4];
    const float* W2  = (const float*)d_in[5];
    const float* b2  = (const float*)d_in[6];
    const float* W3  = (const float*)d_in[7];
    const float* b3  = (const float*)d_in[8];
    float*       out = (float*)d_out;

    unsigned short* Pb = (unsigned short*)d_ws;           // [N_NODES][128] bf16 swizzled (+b1)
    unsigned short* Qb = Pb + (size_t)N_NODES * 128;      // [N_NODES][128] bf16 swizzled
    // ws usage: 51.2 MB

    precompute_mfma<<<512, 256, 0, stream>>>(x, W1, b1, Pb, Qb);
    edge_mfma<<<1536, 256, 0, stream>>>(ei, ef, W1, W2, b2, W3, b3, Pb, Qb, out);
}

// Round 10
// 332.988 us; speedup vs baseline: 1.4229x; 1.0638x over previous
//
#include <hip/hip_runtime.h>

#define N_NODES 100000
#define N_EDGES 1000000

typedef __attribute__((ext_vector_type(8))) short bf16x8;
typedef __attribute__((ext_vector_type(4))) float f32x4;
typedef __attribute__((ext_vector_type(4))) unsigned u32x4;

static __device__ __forceinline__ short f2bf(float f) {
    unsigned u = __float_as_uint(f);
    u = (u + 0x7fffu + ((u >> 16) & 1u)) >> 16;
    return (short)u;
}
static __device__ __forceinline__ float bf2f(unsigned short s) {
    return __uint_as_float(((unsigned)s) << 16);
}
static __device__ __forceinline__ float lrelu(float x) {
    return fmaxf(x, 0.01f * x);   // 0.01x > x iff x < 0
}
// packed f32->bf16 (RNE)
static __device__ __forceinline__ unsigned cvtpk(float lo, float hi) {
    unsigned r;
    asm("v_cvt_pk_bf16_f32 %0, %1, %2" : "=v"(r) : "v"(lo), "v"(hi));
    return r;
}
// non-temporal helpers: single-use streams must not pollute caches
static __device__ __forceinline__ f32x4 ldnt_f4(const float* p) {
    return __builtin_nontemporal_load((const f32x4*)p);
}
static __device__ __forceinline__ int ldnt_i(const int* p) {
    return __builtin_nontemporal_load(p);
}

// ---------------------------------------------------------------------------
// Precompute v3: P/Q tables in COALESCING-OPTIMAL row swizzle.
//   channel 16*mt + 4*q + r  ->  ushort position (mt>>1)*32 + q*8 + (mt&1)*4 + r
// (chunk-major instead of q-major). The edge kernel's chunk-c gather then
// reads, per edge, its 4 q-lanes CONTIGUOUSLY: one fully-used 64-B granule
// per edge per instruction (16 granules/instr) instead of 64 scattered
// quarter-used granules. Same bytes, 4x fewer per-instruction cache lines.
// W1 setup staged via LDS (coalesced); table stores non-temporal.
// ---------------------------------------------------------------------------
__global__ __launch_bounds__(256) void precompute_mfma(
    const float* __restrict__ x, const float* __restrict__ W1,
    const float* __restrict__ b1, unsigned short* __restrict__ Pb,
    unsigned short* __restrict__ Qb)
{
    __shared__ unsigned short w1t[128][264];   // [col][row], 67.6 KB -> 2 blocks/CU
    const int t    = threadIdx.x;
    const int lane = t & 63;
    const int w    = t >> 6;
    const int q    = lane >> 4;
    const int n15  = lane & 15;
    const int chb  = 64 * w;

    // stage W1 rows 0..255 (the x_o / x_d blocks), coalesced read, transposed
    #pragma unroll 4
    for (int i = 0; i < 128; ++i) {
        const int idx = t + 256 * i;           // 0..32767
        const int row = idx >> 7, col = idx & 127;
        w1t[col][row] = (unsigned short)f2bf(W1[idx]);
    }
    __syncthreads();

    // fragment build from LDS (b128, 16-B aligned)
    bf16x8 afrag[4][4];
    #pragma unroll
    for (int mtl = 0; mtl < 4; ++mtl) {
        const int ch = chb + 16 * mtl + n15;
        const int tc = (ch < 128) ? ch : (ch - 128);
        const int rb = (ch < 128) ? 0 : 128;
        #pragma unroll
        for (int ks = 0; ks < 4; ++ks)
            afrag[mtl][ks] = *(const bf16x8*)&w1t[tc][rb + 32 * ks + 8 * q];
    }
    float b1r[16];
    #pragma unroll
    for (int mtl = 0; mtl < 4; ++mtl)
        #pragma unroll
        for (int r = 0; r < 4; ++r) {
            const int ch = chb + 16 * mtl + 4 * q + r;
            b1r[mtl * 4 + r] = (ch < 128) ? b1[ch] : 0.0f;
        }

    unsigned short* tbase = (w < 2) ? Pb : Qb;
    const int mtb = 4 * (w & 1);   // mt base within table

    for (int tile = blockIdx.x; tile < N_NODES / 16; tile += gridDim.x) {
        const int n0 = tile * 16;
        const float* xrow = x + (size_t)(n0 + n15) * 128;

        bf16x8 bfr[4];
        #pragma unroll
        for (int ks = 0; ks < 4; ++ks) {
            f32x4 xa = ldnt_f4(xrow + 32 * ks + 8 * q);
            f32x4 xb = ldnt_f4(xrow + 32 * ks + 8 * q + 4);
            u32x4 bu;
            bu[0] = cvtpk(xa[0], xa[1]);
            bu[1] = cvtpk(xa[2], xa[3]);
            bu[2] = cvtpk(xb[0], xb[1]);
            bu[3] = cvtpk(xb[2], xb[3]);
            bfr[ks] = __builtin_bit_cast(bf16x8, bu);
        }
        #pragma unroll
        for (int mtl = 0; mtl < 4; ++mtl) {
            f32x4 acc = {0.f, 0.f, 0.f, 0.f};
            #pragma unroll
            for (int ks = 0; ks < 4; ++ks)
                acc = __builtin_amdgcn_mfma_f32_16x16x32_bf16(afrag[mtl][ks], bfr[ks], acc, 0, 0, 0);
            // NEW swizzle: chunk-major position (mt>>1)*32 + q*8 + (mt&1)*4
            const int mt = mtb + mtl;
            unsigned* dst = (unsigned*)(tbase + (size_t)(n0 + n15) * 128
                                        + (mt >> 1) * 32 + q * 8 + (mt & 1) * 4);
            __builtin_nontemporal_store(cvtpk(acc[0] + b1r[mtl * 4 + 0], acc[1] + b1r[mtl * 4 + 1]), dst);
            __builtin_nontemporal_store(cvtpk(acc[2] + b1r[mtl * 4 + 2], acc[3] + b1r[mtl * 4 + 3]), dst + 1);
        }
    }
}

// ---------------------------------------------------------------------------
// Edge kernel v8: identical structure to v5 (best measured), but gathers use
// the chunk-major table swizzle: chunk c reads row + c*64B + q*16B, so the
// 4 q-lanes of each edge are CONTIGUOUS -> 16 fully-used 64-B granules per
// gather instruction instead of 64 quarter-used ones (4x less TA divergence
// serialization, the hypothesized shared bottleneck behind R3/R6/R7 nulls).
// Channel->lane mapping is unchanged; phase 1/2/3 code untouched.
// ---------------------------------------------------------------------------
__global__ __launch_bounds__(256, 3) void edge_mfma(
    const int* __restrict__ ei, const float* __restrict__ ef,
    const float* __restrict__ W1, const float* __restrict__ W2,
    const float* __restrict__ b2, const float* __restrict__ W3,
    const float* __restrict__ b3, const unsigned short* __restrict__ Pb,
    const unsigned short* __restrict__ Qb, float* __restrict__ out)
{
    __shared__ unsigned short w2s[16 * 64 * 8];   // 16 frags x 64 lanes x 16B = 16 KiB
    __shared__ unsigned short a1s[8 * 64 * 8];    // 8 frags x 64 lanes x 16B  =  8 KiB
    const int t    = threadIdx.x;
    const int lane = t & 63;
    const int w    = t >> 6;
    const int q    = lane >> 4;
    const int n15  = lane & 15;

    // stage W1c^T frags (edge-feature slice): wave w writes mt = 2w, 2w+1
    #pragma unroll
    for (int i = 0; i < 2; ++i) {
        const int mt = 2 * w + i;
        bf16x8 f;
        #pragma unroll
        for (int j = 0; j < 8; ++j)
            f[j] = f2bf(W1[(size_t)(256 + 8 * q + j) * 128 + 16 * mt + n15]);
        *(bf16x8*)&a1s[(mt * 64 + lane) * 8] = f;
    }

    // stage W2^T frags in PERMUTED k-order: wave w writes mt2 = w
    // chunk ks, lane q, reg j  <->  channel 32ks + (j<4 ? 4q+j : 16+4q+j-4)
    {
        const int mt2 = w;
        #pragma unroll
        for (int ks = 0; ks < 4; ++ks) {
            bf16x8 f;
            #pragma unroll
            for (int j = 0; j < 8; ++j) {
                const int ch = 32 * ks + ((j < 4) ? (4 * q + j) : (16 + 4 * q + (j - 4)));
                f[j] = f2bf(W2[(size_t)ch * 64 + 16 * mt2 + n15]);
            }
            *(bf16x8*)&w2s[(((mt2 << 2) | ks) * 64 + lane) * 8] = f;
        }
    }

    // b2 / W3 packed as bf16 pairs (low = b2, high = W3)
    unsigned b2w3[16];
    #pragma unroll
    for (int mt2 = 0; mt2 < 4; ++mt2)
        #pragma unroll
        for (int r = 0; r < 4; ++r) {
            const int ch = 16 * mt2 + 4 * q + r;
            b2w3[mt2 * 4 + r] = (unsigned)(unsigned short)f2bf(b2[ch])
                              | ((unsigned)(unsigned short)f2bf(W3[ch]) << 16);
        }
    const float b3v = b3[0];

    __syncthreads();   // a1s/w2s visible to all waves (only barrier in the kernel)

    const int nTiles  = N_EDGES / 16;          // 62500
    const int wid     = blockIdx.x * 4 + w;
    const int wstride = gridDim.x * 4;
    if (wid >= nTiles) return;

    // ---- prologue: generations 0 (idx+ef+gather) and 1 (idx+ef) ----
    int tile0 = wid;
    int tile1 = tile0 + wstride;
    bool have1 = tile1 < nTiles;

    int oi0, di0; f32x4 ea0, eb0;
    {
        const int e0 = tile0 * 16;
        oi0 = ldnt_i(&ei[e0 + n15]);
        di0 = ldnt_i(&ei[N_EDGES + e0 + n15]);
        ea0 = ldnt_f4(ef + (size_t)(e0 + n15) * 32 + 8 * q);
        eb0 = ldnt_f4(ef + (size_t)(e0 + n15) * 32 + 8 * q + 4);
    }
    int oi1 = 0, di1 = 0; f32x4 ea1 = ea0, eb1 = eb0;
    if (have1) {
        const int e1 = tile1 * 16;
        oi1 = ldnt_i(&ei[e1 + n15]);
        di1 = ldnt_i(&ei[N_EDGES + e1 + n15]);
        ea1 = ldnt_f4(ef + (size_t)(e1 + n15) * 32 + 8 * q);
        eb1 = ldnt_f4(ef + (size_t)(e1 + n15) * 32 + 8 * q + 4);
    }
    bf16x8 pvb[4], qvb[4];
    {
        const unsigned short* prow = Pb + (size_t)oi0 * 128 + q * 8;
        const unsigned short* qrow = Qb + (size_t)di0 * 128 + q * 8;
        #pragma unroll
        for (int c = 0; c < 4; ++c) {
            pvb[c] = *(const bf16x8*)(prow + 32 * c);
            qvb[c] = *(const bf16x8*)(qrow + 32 * c);
        }
    }

    while (true) {
        // convert current ef to B-frag
        u32x4 befu;
        befu[0] = cvtpk(ea0[0], ea0[1]);
        befu[1] = cvtpk(ea0[2], ea0[3]);
        befu[2] = cvtpk(eb0[0], eb0[1]);
        befu[3] = cvtpk(eb0[2], eb0[3]);
        const bf16x8 bef = __builtin_bit_cast(bf16x8, befu);

        // issue generation-2 idx + ef loads (consumed next-next iteration)
        const int  tile2 = tile1 + wstride;
        const bool have2 = have1 && (tile2 < nTiles);
        int oi2 = oi1, di2 = di1; f32x4 ea2 = ea1, eb2 = eb1;
        if (have2) {
            const int e2 = tile2 * 16;
            oi2 = ldnt_i(&ei[e2 + n15]);
            di2 = ldnt_i(&ei[N_EDGES + e2 + n15]);
            ea2 = ldnt_f4(ef + (size_t)(e2 + n15) * 32 + 8 * q);
            eb2 = ldnt_f4(ef + (size_t)(e2 + n15) * 32 + 8 * q + 4);
        }

        // ---- phase 1: 8 MFMA + epilogue -> hfu (registers, no LDS) ----
        u32x4 hfu[4];
        #pragma unroll
        for (int mt = 0; mt < 8; ++mt) {
            const bf16x8 a1f = *(const bf16x8*)&a1s[(mt * 64 + lane) * 8];
            f32x4 z = {0.f, 0.f, 0.f, 0.f};
            f32x4 h = __builtin_amdgcn_mfma_f32_16x16x32_bf16(a1f, bef, z, 0, 0, 0);
            const int c = mt >> 1, off = (mt & 1) * 4;
            float v0 = lrelu(h[0] + bf2f((unsigned short)pvb[c][off + 0]) + bf2f((unsigned short)qvb[c][off + 0]));
            float v1 = lrelu(h[1] + bf2f((unsigned short)pvb[c][off + 1]) + bf2f((unsigned short)qvb[c][off + 1]));
            float v2 = lrelu(h[2] + bf2f((unsigned short)pvb[c][off + 2]) + bf2f((unsigned short)qvb[c][off + 2]));
            float v3 = lrelu(h[3] + bf2f((unsigned short)pvb[c][off + 3]) + bf2f((unsigned short)qvb[c][off + 3]));
            hfu[mt >> 1][(mt & 1) * 2 + 0] = cvtpk(v0, v1);
            hfu[mt >> 1][(mt & 1) * 2 + 1] = cvtpk(v2, v3);
        }

        // pvb/qvb now dead: issue next tile's gathers (indices loaded a full
        // iteration ago). Chunk-major layout -> contiguous 64-B per edge.
        if (have1) {
            const unsigned short* prow = Pb + (size_t)oi1 * 128 + q * 8;
            const unsigned short* qrow = Qb + (size_t)di1 * 128 + q * 8;
            #pragma unroll
            for (int c = 0; c < 4; ++c) {
                pvb[c] = *(const bf16x8*)(prow + 32 * c);
                qvb[c] = *(const bf16x8*)(qrow + 32 * c);
            }
        }

        // ---- phase 2: 16 MFMA, B-operand straight from hfu registers ----
        f32x4 acc2[4] = {{0.f,0.f,0.f,0.f},{0.f,0.f,0.f,0.f},{0.f,0.f,0.f,0.f},{0.f,0.f,0.f,0.f}};
        #pragma unroll
        for (int ks = 0; ks < 4; ++ks) {
            const bf16x8 hfrag = __builtin_bit_cast(bf16x8, hfu[ks]);
            #pragma unroll
            for (int mt2 = 0; mt2 < 4; ++mt2) {
                const bf16x8 a2f = *(const bf16x8*)&w2s[(((mt2 << 2) | ks) * 64 + lane) * 8];
                acc2[mt2] = __builtin_amdgcn_mfma_f32_16x16x32_bf16(a2f, hfrag, acc2[mt2], 0, 0, 0);
            }
        }

        // ---- phase 3: bias, leaky, dot W3, 4-way lane reduce ----
        float s = 0.0f;
        #pragma unroll
        for (int mt2 = 0; mt2 < 4; ++mt2)
            #pragma unroll
            for (int r = 0; r < 4; ++r) {
                const unsigned u = b2w3[mt2 * 4 + r];
                float v = acc2[mt2][r] + bf2f((unsigned short)(u & 0xffffu));
                v = lrelu(v);
                s += v * __uint_as_float(u & 0xffff0000u);
            }
        s += __shfl_xor(s, 16);
        s += __shfl_xor(s, 32);
        if (q == 0) __builtin_nontemporal_store(s + b3v, &out[tile0 * 16 + n15]);

        if (!have1) break;
        tile0 = tile1; tile1 = tile2; have1 = have2;
        oi1 = oi2; di1 = di2;
        ea0 = ea1; eb0 = eb1; ea1 = ea2; eb1 = eb2;
    }
}

extern "C" void kernel_launch(void* const* d_in, const int* in_sizes, int n_in,
                              void* d_out, int out_size, void* d_ws, size_t ws_size,
                              hipStream_t stream) {
    const float* x   = (const float*)d_in[0];
    const int*   ei  = (const int*)d_in[1];
    const float* ef  = (const float*)d_in[2];
    const float* W1  = (const float*)d_in[3];
    const float* b1  = (const float*)d_in[4];
    const float* W2  = (const float*)d_in[5];
    const float* b2  = (const float*)d_in[6];
    const float* W3  = (const float*)d_in[7];
    const float* b3  = (const float*)d_in[8];
    float*       out = (float*)d_out;

    unsigned short* Pb = (unsigned short*)d_ws;           // [N_NODES][128] bf16, chunk-major swizzle (+b1)
    unsigned short* Qb = Pb + (size_t)N_NODES * 128;      // [N_NODES][128] bf16, chunk-major swizzle
    // ws usage: 51.2 MB

    precompute_mfma<<<512, 256, 0, stream>>>(x, W1, b1, Pb, Qb);
    edge_mfma<<<1536, 256, 0, stream>>>(ei, ef, W1, W2, b2, W3, b3, Pb, Qb, out);
}